// Round 16
// baseline (420.104 us; speedup 1.0000x reference)
//
#include <hip/hip_runtime.h>
#include <math.h>

#define BB 4
#define NPT 4096
#define DP 32
#define DD 128
#define KNB 36

typedef unsigned short ushort_t;
typedef unsigned int uint_t;
typedef unsigned long long ull;
typedef __attribute__((ext_vector_type(8))) short bf16x8;
typedef __attribute__((ext_vector_type(4))) float f32x4;
typedef __attribute__((ext_vector_type(4))) uint_t u32x4;

__device__ __forceinline__ ushort_t f2bf(float f) {
    unsigned u = __float_as_uint(f);
    unsigned r = (u + 0x7FFFu + ((u >> 16) & 1u)) >> 16;  // RNE
    return (ushort_t)r;
}
// single-instruction RNE pair convert: low = lo, high = hi
__device__ __forceinline__ uint_t cvtpk(float lo, float hi) {
    uint_t r;
    asm("v_cvt_pk_bf16_f32 %0, %1, %2" : "=v"(r) : "v"(lo), "v"(hi));
    return r;
}
__device__ __forceinline__ ushort_t f2bf1(float f) { return (ushort_t)cvtpk(f, f); }
__device__ __forceinline__ float bf2f(ushort_t h) {
    return __uint_as_float((unsigned)h << 16);
}
// XOR chunk swizzle (MFMA-read buffers only): row-major [R][128] bf16
__device__ __forceinline__ int swzi(int r, int f) {
    return (r << 7) + (((f >> 3) ^ (r & 15)) << 3) + (f & 7);
}

// ---------------- kernel 0: convert the 4 big weight matrices to bf16 ----------------
__global__ __launch_bounds__(256) void k_wcvt(const float* __restrict__ Wd2,
                                              const float* __restrict__ Wg1,
                                              const float* __restrict__ Wg2,
                                              const float* __restrict__ W2,
                                              ushort_t* __restrict__ wb) {
    int i = blockIdx.x * 256 + threadIdx.x;  // 16384 per matrix
    wb[i]           = f2bf(Wd2[i]);
    wb[i + 16384]   = f2bf(Wg1[i]);
    wb[i + 32768]   = f2bf(Wg2[i]);
    wb[i + 49152]   = f2bf(W2[i]);
}

// ---------------- kernel 1: x = features @ W1.T + b1 (+bf16 copy) ; xyz4 — FROZEN math -
__global__ __launch_bounds__(256) void k_x(const float* __restrict__ feat,
                                           const float* __restrict__ xyz,
                                           const float* __restrict__ W1,
                                           const float* __restrict__ b1,
                                           float* __restrict__ x,
                                           ushort_t* __restrict__ xb,
                                           float4* __restrict__ xyz4) {
    int g = threadIdx.x >> 7;
    int row = blockIdx.x * 2 + g;
    int t = threadIdx.x & 127;
    __shared__ float sf[2][DP];
    if (t < DP) sf[g][t] = feat[row * DP + t];
    __syncthreads();
    float acc = 0.f;
#pragma unroll
    for (int c = 0; c < DP; ++c) acc = fmaf(sf[g][c], W1[t * DP + c], acc);
    float xv = acc + b1[t];
    x[(size_t)row * DD + t] = xv;
    xb[(size_t)row * DD + t] = f2bf1(xv);
    if (t == 0) {
        float a = xyz[row * 3 + 0], b = xyz[row * 3 + 1], c = xyz[row * 3 + 2];
        float s = __fadd_rn(__fadd_rn(__fmul_rn(a, a), __fmul_rn(b, b)),
                            __fmul_rn(c, c));
        xyz4[row] = make_float4(a, b, c, s);
    }
}

// ---------------- kernel 2: fused KNN + per-2-point transformer, bf16 MFMA -------------
// KNN (bit-frozen numpy-mirror distances, histogram select + wave-0 bitonic sort)
// executed in-block for both points; scratch (16 KB) aliases Abuf (first used at h1).
// Then: M = 72 rows (2 pts x 36 nbrs); 5 M-tiles, tile 4's rows 72..79 read past Abuf
// into Vbuf (defined garbage, discarded). Abuf swizzled (MFMA A-reads); Vbuf +
// attn_pre linear (offset-immediate folding in softmax).
__global__ __launch_bounds__(256) void k_fused3(
    const float4* __restrict__ xyz4, const float* __restrict__ x,
    const ushort_t* __restrict__ xb,
    const float* __restrict__ Wd1, const float* __restrict__ bd1,
    const float* __restrict__ bd2, const float* __restrict__ bg1,
    const float* __restrict__ bg2, const float* __restrict__ b2,
    const ushort_t* __restrict__ Wd2b, const ushort_t* __restrict__ Wg1b,
    const ushort_t* __restrict__ Wg2b, const ushort_t* __restrict__ W2b,
    float* __restrict__ out_res, float* __restrict__ out_attn) {

    const int p0 = blockIdx.x * 2;      // first global point
    const int b = p0 >> 12;
    const int t = threadIdx.x;
    const int w = t >> 6;
    const int l = t & 63;
    const int q4 = l >> 4;

    // Abuf first, Vbuf immediately after: tile-4 A-reads (rows 72..79) land in Vbuf.
    __shared__ __align__(16) ushort_t Abuf[72 * 128];   // 18 KB: KNN scratch -> h1/g_in/h2 (swz) -> attn_pre (linear) -> res (swz)
    __shared__ __align__(16) ushort_t Vbuf[72 * 128];   // 18 KB: xk -> vpe (LINEAR)
    __shared__ int sidxb[72];
    __shared__ float dxb[72 * 3];
    __shared__ float Wd1s[384];
    __shared__ float bd1s[128];
    __shared__ int wsum[4];
    __shared__ ull wred[4];
    __shared__ ull sbest;
    __shared__ int sC, sCnt;

    // hoisted per-thread constants (cols c0, c1 of this wave)
    const int c0 = ((w * 2) << 4) + (l & 15);
    const int c1 = c0 + 16;
    float xn_r[2][2];
#pragma unroll
    for (int g = 0; g < 2; ++g) {
        xn_r[0][g] = x[(size_t)(p0 + g) * DD + c0];
        xn_r[1][g] = x[(size_t)(p0 + g) * DD + c1];
    }
    const float bd2_r[2] = {bd2[c0], bd2[c1]};
    const float bg1_r[2] = {bg1[c0], bg1[c1]};
    const float bg2_r[2] = {bg2[c0], bg2[c1]};
    const float b2_r[2]  = {b2[c0],  b2[c1]};

    // ---- stage Wd1/bd1 (separate LDS; first KNN barrier publishes) ----
    if (t < 128) bd1s[t] = bd1[t];
    if (t >= 128 && t < 224) {  // 384 floats via float4: 96 threads
        int i = t - 128;
        reinterpret_cast<float4*>(Wd1s)[i] = reinterpret_cast<const float4*>(Wd1)[i];
    }

    // ================= KNN phase (bit-frozen) — scratch aliases Abuf =================
    {
        ull* cand = reinterpret_cast<ull*>(Abuf);       // 16 KB <= 18 KB
        uint_t* hist4 = reinterpret_cast<uint_t*>(Abuf);
        const float4* bp = xyz4 + (size_t)b * NPT;

#pragma unroll 1
        for (int gg = 0; gg < 2; ++gg) {
            const float4 q = xyz4[p0 + gg];
#pragma unroll
            for (int i = 0; i < 16; ++i) hist4[t + (i << 8)] = 0;
            if (t == 0) sCnt = 0;
            __syncthreads();

            // pass 1: distances -> keys (regs) + replicated histogram
            uint_t k16[16];
#pragma unroll
            for (int i = 0; i < 16; ++i) {
                int m = t + (i << 8);
                float4 p = bp[m];
                float d0 = __fmul_rn(q.x, p.x);
                float d1 = __fmaf_rn(q.y, p.y, d0);
                float dot = __fmaf_rn(q.z, p.z, d1);
                float d = __fsub_rn(__fadd_rn(q.w, p.w), __fmul_rn(2.0f, dot));
                unsigned u = __float_as_uint(d);
                u = (u & 0x80000000u) ? ~u : (u | 0x80000000u);
                k16[i] = u;
                int bin = (u < 0x80000000u) ? 0 : (int)((u - 0x80000000u) >> 21);
                atomicAdd(&hist4[(bin << 2) | (t & 3)], 1u);
            }
            __syncthreads();

            // scan: thread t owns bins 4t..4t+3 (= hist4[16t..16t+15])
            int s_t = 0;
#pragma unroll
            for (int i = 0; i < 16; ++i) s_t += (int)hist4[(t << 4) + i];
            int v = s_t;
            for (int off = 1; off < 64; off <<= 1) {
                int o = __shfl_up(v, off, 64);
                if (l >= off) v += o;
            }
            if (l == 63) wsum[w] = v;
            __syncthreads();
            int base = 0;
            for (int w0 = 0; w0 < w; ++w0) base += wsum[w0];
            int cumIncl = base + v, cumExcl = cumIncl - s_t;
            if (cumExcl < KNB && cumIncl >= KNB) {
                int run = cumExcl;
#pragma unroll
                for (int j = 0; j < 4; ++j) {
                    int bb = (t << 2) + j;
                    int h = (int)(hist4[(bb << 2) + 0] + hist4[(bb << 2) + 1] +
                                  hist4[(bb << 2) + 2] + hist4[(bb << 2) + 3]);
                    if (run + h >= KNB) { sC = bb; break; }
                    run += h;
                }
            }
            __syncthreads();      // hist4 dead past this point; cand may overwrite
            const int C = sC;

            // pass 2: compact candidates with bin <= C
#pragma unroll
            for (int i = 0; i < 16; ++i) {
                uint_t u = k16[i];
                int bin = (u < 0x80000000u) ? 0 : (int)((u - 0x80000000u) >> 21);
                if (bin <= C) {
                    int p = atomicAdd(&sCnt, 1);
                    if (p < 2048) cand[p] = ((ull)u << 32) | (uint_t)(t + (i << 8));
                }
            }
            __syncthreads();
            const int cnt = sCnt;

            if (cnt <= 64) {  // fast path (~always): wave-0 bitonic sort of 64 keys
                if (w == 0) {
                    ull xk_ = (l < cnt) ? cand[l] : ~0ull;
#pragma unroll
                    for (int k = 2; k <= 64; k <<= 1) {
#pragma unroll
                        for (int j = k >> 1; j > 0; j >>= 1) {
                            ull o = __shfl_xor(xk_, j, 64);
                            bool up = ((l & k) == 0);
                            bool lower = ((l & j) == 0);
                            ull mn = (xk_ < o) ? xk_ : o;
                            ull mx = (xk_ < o) ? o : xk_;
                            xk_ = (up == lower) ? mn : mx;
                        }
                    }
                    if (l < KNB) sidxb[gg * KNB + l] = (int)(xk_ & 0xffffffffu);
                }
            } else if (cnt <= 2048) {  // mid path (rare): block extraction over cand list
                ull lk = ~0ull;
                for (int i = t; i < cnt; i += 256) { ull k = cand[i]; if (k < lk) lk = k; }
                for (int r = 0; r < KNB; ++r) {
                    ull k = lk;
#pragma unroll
                    for (int off = 32; off >= 1; off >>= 1) {
                        ull o = __shfl_down(k, off, 64);
                        if (o < k) k = o;
                    }
                    if (l == 0) wred[w] = k;
                    __syncthreads();
                    if (t == 0) {
                        ull best = wred[0];
                        for (int w0 = 1; w0 < 4; ++w0) if (wred[w0] < best) best = wred[w0];
                        sbest = best;
                        sidxb[gg * KNB + r] = (int)(best & 0xffffffffu);
                    }
                    __syncthreads();
                    ull best = sbest;
                    if (lk == best) {
                        for (int i = t; i < cnt; i += 256)
                            if (cand[i] == best) cand[i] = ~0ull;
                        ull nm = ~0ull;
                        for (int i = t; i < cnt; i += 256) { ull kk = cand[i]; if (kk < nm) nm = kk; }
                        lk = nm;
                    }
                }
            } else {  // slow path (pathological): extraction over all 4096 via bitmap
                uint_t* bm = (uint_t*)cand;  // 4096 bits
                if (t < 128) bm[t] = 0;
                __syncthreads();
                ull lk = ~0ull;
#pragma unroll
                for (int i = 0; i < 16; ++i) {
                    ull k = ((ull)k16[i] << 32) | (uint_t)(t + (i << 8));
                    if (k < lk) lk = k;
                }
                for (int r = 0; r < KNB; ++r) {
                    ull k = lk;
#pragma unroll
                    for (int off = 32; off >= 1; off >>= 1) {
                        ull o = __shfl_down(k, off, 64);
                        if (o < k) k = o;
                    }
                    if (l == 0) wred[w] = k;
                    __syncthreads();
                    if (t == 0) {
                        ull best = wred[0];
                        for (int w0 = 1; w0 < 4; ++w0) if (wred[w0] < best) best = wred[w0];
                        sbest = best;
                        sidxb[gg * KNB + r] = (int)(best & 0xffffffffu);
                    }
                    __syncthreads();
                    ull best = sbest;
                    int bi = (int)(best & 0xffffffffu);
                    if ((bi & 255) == t) {
                        bm[bi >> 5] |= (1u << (bi & 31));
                        ull nm = ~0ull;
#pragma unroll
                        for (int i = 0; i < 16; ++i) {
                            int m = t + (i << 8);
                            if ((bm[m >> 5] >> (m & 31)) & 1u) continue;
                            ull kk = ((ull)k16[i] << 32) | (uint_t)m;
                            if (kk < nm) nm = kk;
                        }
                        lk = nm;
                    }
                }
            }
            __syncthreads();   // sidxb visible; scratch free for next point / h1
        }
    }

    // ================= transformer phase (identical to R14) =================

    // ---- dxyz (from xyz4 — same float values as raw xyz) ----
    if (t < 72) {
        int g = (t >= KNB);
        float4 pq = xyz4[p0 + g];
        float4 pj = xyz4[(size_t)(b << 12) + sidxb[t]];
        dxb[t * 3 + 0] = pq.x - pj.x;
        dxb[t * 3 + 1] = pq.y - pj.y;
        dxb[t * 3 + 2] = pq.z - pj.z;
    }
    // ---- gather xk -> Vbuf (LINEAR): one bf16x8 global load + b128 LDS store per iter --
    for (int e = t; e < 72 * 16; e += 256) {
        int r = e >> 4, cb = e & 15;
        bf16x8 v = *reinterpret_cast<const bf16x8*>(
            xb + ((size_t)(b << 12) + sidxb[r]) * DD + (cb << 3));
        *reinterpret_cast<bf16x8*>(&Vbuf[(r << 7) + (cb << 3)]) = v;
    }
    __syncthreads();

    // ---- h1 = relu(d_in @ Wd1.T + bd1) -> Abuf (swizzled b128 stores) ----
    {
        const int cb = t & 15;
        float w0v[8], w1v[8], w2v[8], bv[8];
#pragma unroll
        for (int u = 0; u < 8; ++u) {
            int f = (cb << 3) + u;
            w0v[u] = Wd1s[f * 3 + 0];
            w1v[u] = Wd1s[f * 3 + 1];
            w2v[u] = Wd1s[f * 3 + 2];
            bv[u]  = bd1s[f];
        }
#pragma unroll
        for (int i = 0; i < 5; ++i) {
            int r = (t >> 4) + (i << 4);
            if (r < 72) {
                float dx0 = dxb[r * 3 + 0], dx1 = dxb[r * 3 + 1], dx2 = dxb[r * 3 + 2];
                float v[8];
#pragma unroll
                for (int u = 0; u < 8; ++u)
                    v[u] = fmaxf(fmaf(w0v[u], dx0, fmaf(w1v[u], dx1, w2v[u] * dx2)) + bv[u], 0.f);
                u32x4 pk = {cvtpk(v[0], v[1]), cvtpk(v[2], v[3]),
                            cvtpk(v[4], v[5]), cvtpk(v[6], v[7])};
                *reinterpret_cast<u32x4*>(&Abuf[(r << 7) + ((cb ^ (r & 15)) << 3)]) = pk;
            }
        }
    }
    __syncthreads();

    const f32x4 z4 = {0.f, 0.f, 0.f, 0.f};

    // GEMM over Abuf with weights Wb; acc[5][2] per wave. Wave w owns N-cols [w*32,w*32+32).
    auto run_gemm = [&](const ushort_t* Wb, f32x4 acc[5][2]) {
        bf16x8 bfrag[2][4];
#pragma unroll
        for (int n2 = 0; n2 < 2; ++n2)
#pragma unroll
            for (int kt = 0; kt < 4; ++kt) {
                int f = ((w * 2 + n2) << 4) + (l & 15);
                int k = (kt << 5) + ((l >> 4) << 3);
                bfrag[n2][kt] = *reinterpret_cast<const bf16x8*>(Wb + f * 128 + k);
            }
        __builtin_amdgcn_s_setprio(1);
#pragma unroll
        for (int mt = 0; mt < 5; ++mt) {
#pragma unroll
            for (int kt = 0; kt < 4; ++kt) {
                int r = (mt << 4) + (l & 15);
                int cs = ((kt << 2) + (l >> 4)) ^ (l & 15);
                bf16x8 a = *reinterpret_cast<const bf16x8*>(&Abuf[(r << 7) + (cs << 3)]);
                acc[mt][0] = __builtin_amdgcn_mfma_f32_16x16x32_bf16(a, bfrag[0][kt], acc[mt][0], 0, 0, 0);
                acc[mt][1] = __builtin_amdgcn_mfma_f32_16x16x32_bf16(a, bfrag[1][kt], acc[mt][1], 0, 0, 0);
            }
        }
        __builtin_amdgcn_s_setprio(0);
    };

    // ---- GEMM1: pe = h1 @ Wd2.T + bd2 ; vpe = xk + pe (linear RMW) ; g_in -> Abuf swz --
    {
        f32x4 acc[5][2];
#pragma unroll
        for (int mt = 0; mt < 5; ++mt) { acc[mt][0] = z4; acc[mt][1] = z4; }
        run_gemm(Wd2b, acc);
        __syncthreads();  // everyone done reading Abuf(h1)
#pragma unroll
        for (int mt = 0; mt < 5; ++mt) {
            int row0 = (mt << 4) + (q4 << 2);
            if (row0 < 72) {
                int g = (row0 >= KNB);
#pragma unroll
                for (int n2 = 0; n2 < 2; ++n2) {
                    int col = (n2 == 0) ? c0 : c1;
                    float xn_sel = xn_r[n2][g];
#pragma unroll
                    for (int rr = 0; rr < 4; ++rr) {
                        int row = row0 + rr;
                        int vs = (row << 7) + col;       // linear
                        float pe = acc[mt][n2][rr] + bd2_r[n2];
                        float xk = bf2f(Vbuf[vs]);
                        Vbuf[vs] = f2bf1(xk + pe);
                        float gin = (xn_sel - xk) + pe;
                        Abuf[swzi(row, col)] = f2bf1(gin);
                    }
                }
            }
        }
        __syncthreads();
    }

    // ---- GEMM2: h2 = relu(g_in @ Wg1.T + bg1) -> Abuf swz ----
    {
        f32x4 acc[5][2];
#pragma unroll
        for (int mt = 0; mt < 5; ++mt) { acc[mt][0] = z4; acc[mt][1] = z4; }
        run_gemm(Wg1b, acc);
        __syncthreads();
#pragma unroll
        for (int mt = 0; mt < 5; ++mt) {
            int row0 = (mt << 4) + (q4 << 2);
            if (row0 < 72) {
#pragma unroll
                for (int n2 = 0; n2 < 2; ++n2) {
                    int col = (n2 == 0) ? c0 : c1;
#pragma unroll
                    for (int rr = 0; rr < 4; ++rr)
                        Abuf[swzi(row0 + rr, col)] = f2bf1(fmaxf(acc[mt][n2][rr] + bg1_r[n2], 0.f));
                }
            }
        }
        __syncthreads();
    }

    // ---- GEMM3: attn_pre = h2 @ Wg2.T + bg2 -> Abuf LINEAR ----
    {
        f32x4 acc[5][2];
#pragma unroll
        for (int mt = 0; mt < 5; ++mt) { acc[mt][0] = z4; acc[mt][1] = z4; }
        run_gemm(Wg2b, acc);
        __syncthreads();  // all reads of Abuf(h2) done before overwrite
#pragma unroll
        for (int mt = 0; mt < 5; ++mt) {
            int row0 = (mt << 4) + (q4 << 2);
            if (row0 < 72) {
#pragma unroll
                for (int n2 = 0; n2 < 2; ++n2) {
                    int col = (n2 == 0) ? c0 : c1;
#pragma unroll
                    for (int rr = 0; rr < 4; ++rr)
                        Abuf[((row0 + rr) << 7) + col] = f2bf1(acc[mt][n2][rr] + bg2_r[n2]);
                }
            }
        }
        __syncthreads();
    }

    // ---- softmax over K (36 rows per point) + attn out + PV reduce ----
    const float cexp = 0.12751744f;  // (1/sqrt(128)) * log2(e)
    float ra;
    {
        int g = t >> 7, f = t & 127;
        const ushort_t* sbase = Abuf + (g * KNB << 7) + f;   // attn_pre
        const ushort_t* vbase = Vbuf + (g * KNB << 7) + f;   // vpe
        float p[KNB];
        float m = -__builtin_inff();
#pragma unroll
        for (int kk = 0; kk < KNB; ++kk) {
            p[kk] = bf2f(sbase[kk << 7]);
            m = fmaxf(m, p[kk]);
        }
        float mc = m * cexp;
        float sum = 0.f;
#pragma unroll
        for (int kk = 0; kk < KNB; ++kk) {
            float e_ = __builtin_amdgcn_exp2f(fmaf(p[kk], cexp, -mc));
            p[kk] = e_;
            sum += e_;
        }
        float inv = 1.f / sum;
        ra = 0.f;
        float* obase = out_attn + ((size_t)(p0 + g) * KNB) * DD + f;
#pragma unroll
        for (int kk = 0; kk < KNB; ++kk) {
            float a_ = p[kk] * inv;
            obase[(size_t)kk * DD] = a_;
            ra = fmaf(a_, bf2f(vbase[kk << 7]), ra);
        }
    }
    __syncthreads();   // all attn_pre/vpe reads done before res overwrites Abuf
    {
        int g = t >> 7, f = t & 127;
        Abuf[swzi(g, f)] = f2bf1(ra);
    }
    __syncthreads();

    // ---- final: out_res = res @ W2.T + b2 + xn (1 M-tile; rows 0..1 valid) ----
    {
        f32x4 acc0 = z4, acc1 = z4;
#pragma unroll
        for (int kt = 0; kt < 4; ++kt) {
            int r = (l & 15);
            int cs = ((kt << 2) + (l >> 4)) ^ (l & 15);
            bf16x8 a = *reinterpret_cast<const bf16x8*>(&Abuf[(r << 7) + (cs << 3)]);
            int k = (kt << 5) + ((l >> 4) << 3);
            bf16x8 b0 = *reinterpret_cast<const bf16x8*>(W2b + c0 * 128 + k);
            bf16x8 b1 = *reinterpret_cast<const bf16x8*>(W2b + c1 * 128 + k);
            acc0 = __builtin_amdgcn_mfma_f32_16x16x32_bf16(a, b0, acc0, 0, 0, 0);
            acc1 = __builtin_amdgcn_mfma_f32_16x16x32_bf16(a, b1, acc1, 0, 0, 0);
        }
        if ((l >> 4) == 0) {  // rows 0..1 live in lanes 0..15, regs 0..1
#pragma unroll
            for (int rr = 0; rr < 2; ++rr) {
                out_res[(size_t)(p0 + rr) * DD + c0] = acc0[rr] + b2_r[0] + xn_r[0][rr];
                out_res[(size_t)(p0 + rr) * DD + c1] = acc1[rr] + b2_r[1] + xn_r[1][rr];
            }
        }
    }
}

extern "C" void kernel_launch(void* const* d_in, const int* in_sizes, int n_in,
                              void* d_out, int out_size, void* d_ws, size_t ws_size,
                              hipStream_t stream) {
    const float* feat = (const float*)d_in[0];
    const float* xyz = (const float*)d_in[1];
    const float* W1 = (const float*)d_in[2];
    const float* b1 = (const float*)d_in[3];
    const float* W2 = (const float*)d_in[4];
    const float* b2 = (const float*)d_in[5];
    const float* Wd1 = (const float*)d_in[6];
    const float* bd1 = (const float*)d_in[7];
    const float* Wd2 = (const float*)d_in[8];
    const float* bd2 = (const float*)d_in[9];
    const float* Wg1 = (const float*)d_in[10];
    const float* bg1 = (const float*)d_in[11];
    const float* Wg2 = (const float*)d_in[12];
    const float* bg2 = (const float*)d_in[13];

    float* out = (float*)d_out;
    float* out_res = out;                           // [B,N,128]
    float* out_attn = out + (size_t)BB * NPT * DD;  // [B,N,36,128]

    float* ws_x = (float*)d_ws;                          // [B*N*128] f32 (8 MB)
    float4* xyz4 = (float4*)(ws_x + (size_t)BB * NPT * DD);   // [B*N] float4 (256 KB)
    ushort_t* wb = (ushort_t*)(xyz4 + (size_t)BB * NPT); // 4*16384 bf16
    ushort_t* Wd2b = wb;
    ushort_t* Wg1b = wb + 16384;
    ushort_t* Wg2b = wb + 32768;
    ushort_t* W2b = wb + 49152;
    ushort_t* xb = wb + 65536;                            // [B*N*128] bf16 (4 MB)

    hipLaunchKernelGGL(k_wcvt, dim3(64), dim3(256), 0, stream, Wd2, Wg1, Wg2, W2, wb);
    hipLaunchKernelGGL(k_x, dim3(BB * NPT / 2), dim3(256), 0, stream,
                       feat, xyz, W1, b1, ws_x, xb, xyz4);
    hipLaunchKernelGGL(k_fused3, dim3(BB * NPT / 2), dim3(256), 0, stream,
                       xyz4, ws_x, xb, Wd1, bd1, bd2, bg1, bg2, b2,
                       Wd2b, Wg1b, Wg2b, W2b, out_res, out_attn);
}

// Round 17
// 317.232 us; speedup vs baseline: 1.3243x; 1.3243x over previous
//
#include <hip/hip_runtime.h>
#include <math.h>

#define BB 4
#define NPT 4096
#define DP 32
#define DD 128
#define KNB 36

typedef unsigned short ushort_t;
typedef unsigned int uint_t;
typedef unsigned long long ull;
typedef __attribute__((ext_vector_type(8))) short bf16x8;
typedef __attribute__((ext_vector_type(4))) float f32x4;
typedef __attribute__((ext_vector_type(4))) uint_t u32x4;

__device__ __forceinline__ ushort_t f2bf(float f) {
    unsigned u = __float_as_uint(f);
    unsigned r = (u + 0x7FFFu + ((u >> 16) & 1u)) >> 16;  // RNE
    return (ushort_t)r;
}
// single-instruction RNE pair convert: low = lo, high = hi
__device__ __forceinline__ uint_t cvtpk(float lo, float hi) {
    uint_t r;
    asm("v_cvt_pk_bf16_f32 %0, %1, %2" : "=v"(r) : "v"(lo), "v"(hi));
    return r;
}
__device__ __forceinline__ ushort_t f2bf1(float f) { return (ushort_t)cvtpk(f, f); }
__device__ __forceinline__ float bf2f(ushort_t h) {
    return __uint_as_float((unsigned)h << 16);
}
// XOR chunk swizzle (MFMA-read buffers only): row-major [R][128] bf16
__device__ __forceinline__ int swzi(int r, int f) {
    return (r << 7) + (((f >> 3) ^ (r & 15)) << 3) + (f & 7);
}

// ---------------- kernel 0: weights -> bf16 ; xyz -> packed {x,y,z,sq} float4 ----------
// Blocks 0..63: weight conversion. Blocks 64..127: xyz4 (sq bit-frozen numpy order).
__global__ __launch_bounds__(256) void k_wcvt(const float* __restrict__ Wd2,
                                              const float* __restrict__ Wg1,
                                              const float* __restrict__ Wg2,
                                              const float* __restrict__ W2,
                                              const float* __restrict__ xyz,
                                              ushort_t* __restrict__ wb,
                                              float4* __restrict__ xyz4) {
    int t = threadIdx.x;
    if (blockIdx.x < 64) {
        int i = blockIdx.x * 256 + t;  // 16384 per matrix
        wb[i]           = f2bf(Wd2[i]);
        wb[i + 16384]   = f2bf(Wg1[i]);
        wb[i + 32768]   = f2bf(Wg2[i]);
        wb[i + 49152]   = f2bf(W2[i]);
    } else {
        int idx = (blockIdx.x - 64) * 256 + t;  // 16384 points
        float a = xyz[idx * 3 + 0], b = xyz[idx * 3 + 1], c = xyz[idx * 3 + 2];
        float s = __fadd_rn(__fadd_rn(__fmul_rn(a, a), __fmul_rn(b, b)),
                            __fmul_rn(c, c));
        xyz4[idx] = make_float4(a, b, c, s);
    }
}

// ---------------- kernel 1: KNN (hist select + bitonic) + x row-compute — FROZEN math --
// x = features @ W1.T + b1 for this block's row interleaves with the KNN issue stream.
__global__ __launch_bounds__(256) void k_knn2(const float4* __restrict__ xyz4,
                                              const float* __restrict__ feat,
                                              const float* __restrict__ W1,
                                              const float* __restrict__ b1,
                                              float* __restrict__ x,
                                              ushort_t* __restrict__ xb,
                                              int* __restrict__ knn) {
    const int row = blockIdx.x;
    const int b = row >> 12;
    const int t = threadIdx.x;
    const int lane = t & 63, wv = t >> 6;

    __shared__ __align__(16) ull cand[2048];  // 16 KB; aliased as hist4[4096] during pass 1
    __shared__ float sf[DP];
    __shared__ int wsum[4];
    __shared__ ull wred[4];
    __shared__ ull sbest;
    __shared__ int sC, sCnt;

    uint_t* hist4 = (uint_t*)cand;  // hist4[bin*4 + (t&3)] : 4-way replicated

    const float4 q = xyz4[row];
    const float4* bp = xyz4 + (size_t)b * NPT;

    if (t < DP) sf[t] = feat[row * DP + t];
#pragma unroll
    for (int i = 0; i < 16; ++i) hist4[t + (i << 8)] = 0;
    if (t == 0) sCnt = 0;
    __syncthreads();

    // ---- x row-compute (hides in the KNN issue stream; no extra barrier needed) ----
    if (t < 128) {
        float acc = 0.f;
#pragma unroll
        for (int c = 0; c < DP; ++c) acc = fmaf(sf[c], W1[t * DP + c], acc);
        float xv = acc + b1[t];
        x[(size_t)row * DD + t] = xv;
        xb[(size_t)row * DD + t] = f2bf1(xv);
    }

    // pass 1: distances -> keys (regs) + replicated histogram
    uint_t k16[16];
#pragma unroll
    for (int i = 0; i < 16; ++i) {
        int m = t + (i << 8);
        float4 p = bp[m];
        float d0 = __fmul_rn(q.x, p.x);
        float d1 = __fmaf_rn(q.y, p.y, d0);
        float dot = __fmaf_rn(q.z, p.z, d1);
        float d = __fsub_rn(__fadd_rn(q.w, p.w), __fmul_rn(2.0f, dot));
        unsigned u = __float_as_uint(d);
        u = (u & 0x80000000u) ? ~u : (u | 0x80000000u);
        k16[i] = u;
        int bin = (u < 0x80000000u) ? 0 : (int)((u - 0x80000000u) >> 21);
        atomicAdd(&hist4[(bin << 2) | (t & 3)], 1u);
    }
    __syncthreads();

    // scan: thread t owns bins 4t..4t+3 (= hist4[16t..16t+15])
    int s_t = 0;
#pragma unroll
    for (int i = 0; i < 16; ++i) s_t += (int)hist4[(t << 4) + i];
    int v = s_t;
    for (int off = 1; off < 64; off <<= 1) {
        int o = __shfl_up(v, off, 64);
        if (lane >= off) v += o;
    }
    if (lane == 63) wsum[wv] = v;
    __syncthreads();
    int base = 0;
    for (int w0 = 0; w0 < wv; ++w0) base += wsum[w0];
    int cumIncl = base + v, cumExcl = cumIncl - s_t;
    if (cumExcl < KNB && cumIncl >= KNB) {
        int run = cumExcl;
#pragma unroll
        for (int j = 0; j < 4; ++j) {
            int bb = (t << 2) + j;
            int h = (int)(hist4[(bb << 2) + 0] + hist4[(bb << 2) + 1] +
                          hist4[(bb << 2) + 2] + hist4[(bb << 2) + 3]);
            if (run + h >= KNB) { sC = bb; break; }
            run += h;
        }
    }
    __syncthreads();      // hist4 dead past this point; cand may overwrite
    // bin(u) <= C  <=>  (ull)u < 0x80000000 + ((C+1)<<21)  (monotone binning)
    const ull thr = 0x80000000ull + ((ull)(sC + 1) << 21);

    // pass 2: compact candidates (single compare per key)
#pragma unroll
    for (int i = 0; i < 16; ++i) {
        uint_t u = k16[i];
        if ((ull)u < thr) {
            int p = atomicAdd(&sCnt, 1);
            if (p < 2048) cand[p] = ((ull)u << 32) | (uint_t)(t + (i << 8));
        }
    }
    __syncthreads();
    const int cnt = sCnt;

    if (cnt <= 64) {  // fast path (~always): wave-0 bitonic sort of 64 keys
        if (wv == 0) {
            ull x_ = (lane < cnt) ? cand[lane] : ~0ull;
#pragma unroll
            for (int k = 2; k <= 64; k <<= 1) {
#pragma unroll
                for (int j = k >> 1; j > 0; j >>= 1) {
                    ull o = __shfl_xor(x_, j, 64);
                    bool up = ((lane & k) == 0);
                    bool lower = ((lane & j) == 0);
                    ull mn = (x_ < o) ? x_ : o;
                    ull mx = (x_ < o) ? o : x_;
                    x_ = (up == lower) ? mn : mx;
                }
            }
            if (lane < KNB) knn[(size_t)row * KNB + lane] = (int)(x_ & 0xffffffffu);
        }
        return;
    }

    if (cnt <= 2048) {  // mid path (rare): block extraction over cand list
        ull lk = ~0ull;
        for (int i = t; i < cnt; i += 256) { ull k = cand[i]; if (k < lk) lk = k; }
        for (int r = 0; r < KNB; ++r) {
            ull k = lk;
#pragma unroll
            for (int off = 32; off >= 1; off >>= 1) {
                ull o = __shfl_down(k, off, 64);
                if (o < k) k = o;
            }
            if (lane == 0) wred[wv] = k;
            __syncthreads();
            if (t == 0) {
                ull best = wred[0];
                for (int w0 = 1; w0 < 4; ++w0) if (wred[w0] < best) best = wred[w0];
                sbest = best;
                knn[(size_t)row * KNB + r] = (int)(best & 0xffffffffu);
            }
            __syncthreads();
            ull best = sbest;
            if (lk == best) {
                for (int i = t; i < cnt; i += 256)
                    if (cand[i] == best) cand[i] = ~0ull;
                ull nm = ~0ull;
                for (int i = t; i < cnt; i += 256) { ull kk = cand[i]; if (kk < nm) nm = kk; }
                lk = nm;
            }
        }
        return;
    }

    // slow path (pathological): extraction over all 4096 from register keys + LDS bitmap
    {
        uint_t* bm = (uint_t*)cand;  // 4096 bits
        if (t < 128) bm[t] = 0;
        __syncthreads();
        ull lk = ~0ull;
#pragma unroll
        for (int i = 0; i < 16; ++i) {
            ull k = ((ull)k16[i] << 32) | (uint_t)(t + (i << 8));
            if (k < lk) lk = k;
        }
        for (int r = 0; r < KNB; ++r) {
            ull k = lk;
#pragma unroll
            for (int off = 32; off >= 1; off >>= 1) {
                ull o = __shfl_down(k, off, 64);
                if (o < k) k = o;
            }
            if (lane == 0) wred[wv] = k;
            __syncthreads();
            if (t == 0) {
                ull best = wred[0];
                for (int w0 = 1; w0 < 4; ++w0) if (wred[w0] < best) best = wred[w0];
                sbest = best;
                knn[(size_t)row * KNB + r] = (int)(best & 0xffffffffu);
            }
            __syncthreads();
            ull best = sbest;
            int bi = (int)(best & 0xffffffffu);
            if ((bi & 255) == t) {
                bm[bi >> 5] |= (1u << (bi & 31));
                ull nm = ~0ull;
#pragma unroll
                for (int i = 0; i < 16; ++i) {
                    int m = t + (i << 8);
                    if ((bm[m >> 5] >> (m & 31)) & 1u) continue;
                    ull kk = ((ull)k16[i] << 32) | (uint_t)m;
                    if (kk < nm) nm = kk;
                }
                lk = nm;
            }
        }
    }
}

// ---------------- kernel 2: fused per-2-point transformer, bf16 MFMA (R14) ------------
// M = 72 rows (2 pts x 36 nbrs); 5 M-tiles, tile 4's rows 72..79 read past Abuf into
// Vbuf (defined garbage, discarded). Abuf swizzled (MFMA A-reads); Vbuf + attn_pre
// linear (column/row access only -> offset-immediate folding in softmax).
__global__ __launch_bounds__(256) void k_fused2(
    const float4* __restrict__ xyz4, const float* __restrict__ x,
    const ushort_t* __restrict__ xb,
    const int* __restrict__ knn,
    const float* __restrict__ Wd1, const float* __restrict__ bd1,
    const float* __restrict__ bd2, const float* __restrict__ bg1,
    const float* __restrict__ bg2, const float* __restrict__ b2,
    const ushort_t* __restrict__ Wd2b, const ushort_t* __restrict__ Wg1b,
    const ushort_t* __restrict__ Wg2b, const ushort_t* __restrict__ W2b,
    float* __restrict__ out_res, float* __restrict__ out_attn) {

    const int p0 = blockIdx.x * 2;      // first global point
    const int b = p0 >> 12;
    const int t = threadIdx.x;
    const int w = t >> 6;
    const int l = t & 63;
    const int q4 = l >> 4;

    // Abuf first, Vbuf immediately after: tile-4 A-reads (rows 72..79) land in Vbuf.
    __shared__ __align__(16) ushort_t Abuf[72 * 128];   // 18 KB: h1/g_in/h2 (swz) -> attn_pre (linear) -> res (swz)
    __shared__ __align__(16) ushort_t Vbuf[72 * 128];   // 18 KB: xk -> vpe (LINEAR)
    __shared__ int sidxb[72];
    __shared__ float dxb[72 * 3];
    __shared__ float Wd1s[384];
    __shared__ float bd1s[128];

    // hoisted per-thread constants (cols c0, c1 of this wave)
    const int c0 = ((w * 2) << 4) + (l & 15);
    const int c1 = c0 + 16;
    float xn_r[2][2];
#pragma unroll
    for (int g = 0; g < 2; ++g) {
        xn_r[0][g] = x[(size_t)(p0 + g) * DD + c0];
        xn_r[1][g] = x[(size_t)(p0 + g) * DD + c1];
    }
    const float bd2_r[2] = {bd2[c0], bd2[c1]};
    const float bg1_r[2] = {bg1[c0], bg1[c1]};
    const float bg2_r[2] = {bg2[c0], bg2[c1]};
    const float b2_r[2]  = {b2[c0],  b2[c1]};

    // ---- stage indices + Wd1/bd1 ----
    if (t < 72) sidxb[t] = knn[(size_t)p0 * KNB + t];
    if (t >= 72 && t < 200) bd1s[t - 72] = bd1[t - 72];
    if (t >= 128 && t < 224) {  // 384 floats via float4: 96 threads
        int i = t - 128;
        reinterpret_cast<float4*>(Wd1s)[i] = reinterpret_cast<const float4*>(Wd1)[i];
    }
    __syncthreads();

    // ---- dxyz (from xyz4 — same float values as raw xyz) ----
    if (t < 72) {
        int g = (t >= KNB);
        float4 pq = xyz4[p0 + g];
        float4 pj = xyz4[(size_t)(b << 12) + sidxb[t]];
        dxb[t * 3 + 0] = pq.x - pj.x;
        dxb[t * 3 + 1] = pq.y - pj.y;
        dxb[t * 3 + 2] = pq.z - pj.z;
    }
    // ---- gather xk -> Vbuf (LINEAR): one bf16x8 global load + b128 LDS store per iter --
    for (int e = t; e < 72 * 16; e += 256) {
        int r = e >> 4, cb = e & 15;
        bf16x8 v = *reinterpret_cast<const bf16x8*>(
            xb + ((size_t)(b << 12) + sidxb[r]) * DD + (cb << 3));
        *reinterpret_cast<bf16x8*>(&Vbuf[(r << 7) + (cb << 3)]) = v;
    }
    __syncthreads();

    // ---- h1 = relu(d_in @ Wd1.T + bd1) -> Abuf (swizzled b128 stores) ----
    {
        const int cb = t & 15;
        float w0v[8], w1v[8], w2v[8], bv[8];
#pragma unroll
        for (int u = 0; u < 8; ++u) {
            int f = (cb << 3) + u;
            w0v[u] = Wd1s[f * 3 + 0];
            w1v[u] = Wd1s[f * 3 + 1];
            w2v[u] = Wd1s[f * 3 + 2];
            bv[u]  = bd1s[f];
        }
#pragma unroll
        for (int i = 0; i < 5; ++i) {
            int r = (t >> 4) + (i << 4);
            if (r < 72) {
                float dx0 = dxb[r * 3 + 0], dx1 = dxb[r * 3 + 1], dx2 = dxb[r * 3 + 2];
                float v[8];
#pragma unroll
                for (int u = 0; u < 8; ++u)
                    v[u] = fmaxf(fmaf(w0v[u], dx0, fmaf(w1v[u], dx1, w2v[u] * dx2)) + bv[u], 0.f);
                u32x4 pk = {cvtpk(v[0], v[1]), cvtpk(v[2], v[3]),
                            cvtpk(v[4], v[5]), cvtpk(v[6], v[7])};
                *reinterpret_cast<u32x4*>(&Abuf[(r << 7) + ((cb ^ (r & 15)) << 3)]) = pk;
            }
        }
    }
    __syncthreads();

    const f32x4 z4 = {0.f, 0.f, 0.f, 0.f};

    // GEMM over Abuf with weights Wb; acc[5][2] per wave. Wave w owns N-cols [w*32,w*32+32).
    auto run_gemm = [&](const ushort_t* Wb, f32x4 acc[5][2]) {
        bf16x8 bfrag[2][4];
#pragma unroll
        for (int n2 = 0; n2 < 2; ++n2)
#pragma unroll
            for (int kt = 0; kt < 4; ++kt) {
                int f = ((w * 2 + n2) << 4) + (l & 15);
                int k = (kt << 5) + ((l >> 4) << 3);
                bfrag[n2][kt] = *reinterpret_cast<const bf16x8*>(Wb + f * 128 + k);
            }
        __builtin_amdgcn_s_setprio(1);
#pragma unroll
        for (int mt = 0; mt < 5; ++mt) {
#pragma unroll
            for (int kt = 0; kt < 4; ++kt) {
                int r = (mt << 4) + (l & 15);
                int cs = ((kt << 2) + (l >> 4)) ^ (l & 15);
                bf16x8 a = *reinterpret_cast<const bf16x8*>(&Abuf[(r << 7) + (cs << 3)]);
                acc[mt][0] = __builtin_amdgcn_mfma_f32_16x16x32_bf16(a, bfrag[0][kt], acc[mt][0], 0, 0, 0);
                acc[mt][1] = __builtin_amdgcn_mfma_f32_16x16x32_bf16(a, bfrag[1][kt], acc[mt][1], 0, 0, 0);
            }
        }
        __builtin_amdgcn_s_setprio(0);
    };

    // ---- GEMM1: pe = h1 @ Wd2.T + bd2 ; vpe = xk + pe (linear RMW) ; g_in -> Abuf swz --
    {
        f32x4 acc[5][2];
#pragma unroll
        for (int mt = 0; mt < 5; ++mt) { acc[mt][0] = z4; acc[mt][1] = z4; }
        run_gemm(Wd2b, acc);
        __syncthreads();  // everyone done reading Abuf(h1)
#pragma unroll
        for (int mt = 0; mt < 5; ++mt) {
            int row0 = (mt << 4) + (q4 << 2);
            if (row0 < 72) {
                int g = (row0 >= KNB);
#pragma unroll
                for (int n2 = 0; n2 < 2; ++n2) {
                    int col = (n2 == 0) ? c0 : c1;
                    float xn_sel = xn_r[n2][g];
#pragma unroll
                    for (int rr = 0; rr < 4; ++rr) {
                        int row = row0 + rr;
                        int vs = (row << 7) + col;       // linear
                        float pe = acc[mt][n2][rr] + bd2_r[n2];
                        float xk = bf2f(Vbuf[vs]);
                        Vbuf[vs] = f2bf1(xk + pe);
                        float gin = (xn_sel - xk) + pe;
                        Abuf[swzi(row, col)] = f2bf1(gin);
                    }
                }
            }
        }
        __syncthreads();
    }

    // ---- GEMM2: h2 = relu(g_in @ Wg1.T + bg1) -> Abuf swz ----
    {
        f32x4 acc[5][2];
#pragma unroll
        for (int mt = 0; mt < 5; ++mt) { acc[mt][0] = z4; acc[mt][1] = z4; }
        run_gemm(Wg1b, acc);
        __syncthreads();
#pragma unroll
        for (int mt = 0; mt < 5; ++mt) {
            int row0 = (mt << 4) + (q4 << 2);
            if (row0 < 72) {
#pragma unroll
                for (int n2 = 0; n2 < 2; ++n2) {
                    int col = (n2 == 0) ? c0 : c1;
#pragma unroll
                    for (int rr = 0; rr < 4; ++rr)
                        Abuf[swzi(row0 + rr, col)] = f2bf1(fmaxf(acc[mt][n2][rr] + bg1_r[n2], 0.f));
                }
            }
        }
        __syncthreads();
    }

    // ---- GEMM3: attn_pre = h2 @ Wg2.T + bg2 -> Abuf LINEAR ----
    {
        f32x4 acc[5][2];
#pragma unroll
        for (int mt = 0; mt < 5; ++mt) { acc[mt][0] = z4; acc[mt][1] = z4; }
        run_gemm(Wg2b, acc);
        __syncthreads();  // all reads of Abuf(h2) done before overwrite
#pragma unroll
        for (int mt = 0; mt < 5; ++mt) {
            int row0 = (mt << 4) + (q4 << 2);
            if (row0 < 72) {
#pragma unroll
                for (int n2 = 0; n2 < 2; ++n2) {
                    int col = (n2 == 0) ? c0 : c1;
#pragma unroll
                    for (int rr = 0; rr < 4; ++rr)
                        Abuf[((row0 + rr) << 7) + col] = f2bf1(acc[mt][n2][rr] + bg2_r[n2]);
                }
            }
        }
        __syncthreads();
    }

    // ---- softmax over K (36 rows per point) + attn out + PV reduce ----
    const float cexp = 0.12751744f;  // (1/sqrt(128)) * log2(e)
    float ra;
    {
        int g = t >> 7, f = t & 127;
        const ushort_t* sbase = Abuf + (g * KNB << 7) + f;   // attn_pre
        const ushort_t* vbase = Vbuf + (g * KNB << 7) + f;   // vpe
        float p[KNB];
        float m = -__builtin_inff();
#pragma unroll
        for (int kk = 0; kk < KNB; ++kk) {
            p[kk] = bf2f(sbase[kk << 7]);
            m = fmaxf(m, p[kk]);
        }
        float mc = m * cexp;
        float sum = 0.f;
#pragma unroll
        for (int kk = 0; kk < KNB; ++kk) {
            float e_ = __builtin_amdgcn_exp2f(fmaf(p[kk], cexp, -mc));
            p[kk] = e_;
            sum += e_;
        }
        float inv = 1.f / sum;
        ra = 0.f;
        float* obase = out_attn + ((size_t)(p0 + g) * KNB) * DD + f;
#pragma unroll
        for (int kk = 0; kk < KNB; ++kk) {
            float a_ = p[kk] * inv;
            obase[(size_t)kk * DD] = a_;
            ra = fmaf(a_, bf2f(vbase[kk << 7]), ra);
        }
    }
    __syncthreads();   // all attn_pre/vpe reads done before res overwrites Abuf
    {
        int g = t >> 7, f = t & 127;
        Abuf[swzi(g, f)] = f2bf1(ra);
    }
    __syncthreads();

    // ---- final: out_res = res @ W2.T + b2 + xn (1 M-tile; rows 0..1 valid) ----
    {
        f32x4 acc0 = z4, acc1 = z4;
#pragma unroll
        for (int kt = 0; kt < 4; ++kt) {
            int r = (l & 15);
            int cs = ((kt << 2) + (l >> 4)) ^ (l & 15);
            bf16x8 a = *reinterpret_cast<const bf16x8*>(&Abuf[(r << 7) + (cs << 3)]);
            int k = (kt << 5) + ((l >> 4) << 3);
            bf16x8 b0 = *reinterpret_cast<const bf16x8*>(W2b + c0 * 128 + k);
            bf16x8 b1 = *reinterpret_cast<const bf16x8*>(W2b + c1 * 128 + k);
            acc0 = __builtin_amdgcn_mfma_f32_16x16x32_bf16(a, b0, acc0, 0, 0, 0);
            acc1 = __builtin_amdgcn_mfma_f32_16x16x32_bf16(a, b1, acc1, 0, 0, 0);
        }
        if ((l >> 4) == 0) {  // rows 0..1 live in lanes 0..15, regs 0..1
#pragma unroll
            for (int rr = 0; rr < 2; ++rr) {
                out_res[(size_t)(p0 + rr) * DD + c0] = acc0[rr] + b2_r[0] + xn_r[0][rr];
                out_res[(size_t)(p0 + rr) * DD + c1] = acc1[rr] + b2_r[1] + xn_r[1][rr];
            }
        }
    }
}

extern "C" void kernel_launch(void* const* d_in, const int* in_sizes, int n_in,
                              void* d_out, int out_size, void* d_ws, size_t ws_size,
                              hipStream_t stream) {
    const float* feat = (const float*)d_in[0];
    const float* xyz = (const float*)d_in[1];
    const float* W1 = (const float*)d_in[2];
    const float* b1 = (const float*)d_in[3];
    const float* W2 = (const float*)d_in[4];
    const float* b2 = (const float*)d_in[5];
    const float* Wd1 = (const float*)d_in[6];
    const float* bd1 = (const float*)d_in[7];
    const float* Wd2 = (const float*)d_in[8];
    const float* bd2 = (const float*)d_in[9];
    const float* Wg1 = (const float*)d_in[10];
    const float* bg1 = (const float*)d_in[11];
    const float* Wg2 = (const float*)d_in[12];
    const float* bg2 = (const float*)d_in[13];

    float* out = (float*)d_out;
    float* out_res = out;                           // [B,N,128]
    float* out_attn = out + (size_t)BB * NPT * DD;  // [B,N,36,128]

    float* ws_x = (float*)d_ws;                          // [B*N*128] f32 (8 MB)
    float4* xyz4 = (float4*)(ws_x + (size_t)BB * NPT * DD);   // [B*N] float4 (256 KB)
    int* ws_idx = (int*)(xyz4 + (size_t)BB * NPT);       // [B*N*36]
    ushort_t* wb = (ushort_t*)(ws_idx + (size_t)BB * NPT * KNB);  // 4*16384 bf16
    ushort_t* Wd2b = wb;
    ushort_t* Wg1b = wb + 16384;
    ushort_t* Wg2b = wb + 32768;
    ushort_t* W2b = wb + 49152;
    ushort_t* xb = wb + 65536;                            // [B*N*128] bf16 (4 MB)

    hipLaunchKernelGGL(k_wcvt, dim3(128), dim3(256), 0, stream,
                       Wd2, Wg1, Wg2, W2, xyz, wb, xyz4);
    hipLaunchKernelGGL(k_knn2, dim3(BB * NPT), dim3(256), 0, stream,
                       xyz4, feat, W1, b1, ws_x, xb, ws_idx);
    hipLaunchKernelGGL(k_fused2, dim3(BB * NPT / 2), dim3(256), 0, stream,
                       xyz4, ws_x, xb, ws_idx, Wd1, bd1, bd2, bg1, bg2, b2,
                       Wd2b, Wg1b, Wg2b, W2b, out_res, out_attn);
}